// Round 13
// baseline (10530.123 us; speedup 1.0000x reference)
//
#include <hip/hip_runtime.h>

#define UNITS   2048
#define IN_DIM  128
#define T_STEPS 4096
#define NBLK    32
#define TPB     1024
#define BROWS   64    // rows per block
#define NWAVE   16

typedef unsigned int u32;
typedef u32 u32x2v __attribute__((ext_vector_type(2)));
typedef short short8 __attribute__((ext_vector_type(8)));
typedef __bf16 bf16x8 __attribute__((ext_vector_type(8)));
typedef float f32x4 __attribute__((ext_vector_type(4)));

// Zero comm words each call: tag 0 never matches (first polled tag is 1).
__global__ void esn_init(u32* __restrict__ buf) {
    int i = blockIdx.x * blockDim.x + threadIdx.x;
    if (i < 2 * UNITS) buf[i] = 0u;
}

__device__ __forceinline__ unsigned short f2bf(float f) {   // RNE float->bf16 bits
    u32 x = __float_as_uint(f);
    return (unsigned short)((x + 0x7FFFu + ((x >> 16) & 1u)) >> 16);
}

__global__ void __launch_bounds__(TPB, 4) esn_step(
    const float* __restrict__ inp,   // [4096][128]
    const float* __restrict__ s0,    // [2048]
    const float* __restrict__ W,     // [2048][2048] row-major
    const float* __restrict__ Win,   // [2048][128]
    float* __restrict__ out,         // [4096*2048 + 2048]
    u32* __restrict__ buf)           // [2][2048] packed (tag16|bf16) words
{
    const int b    = blockIdx.x;
    const int tid  = threadIdx.x;
    const int lane = tid & 63;
    const int wv   = tid >> 6;       // wave 0..15, all symmetric
    const int h8   = (lane >> 4) * 8;
    const int colr = lane & 15;

    __shared__ unsigned short sB[UNITS];   // bf16 state; [128w,128w+128) PRIVATE to wave w
    __shared__ float red[2][NWAVE][4][16]; // per-wave C partials (parity, wave, row-tile, row)
    __shared__ float s_state[BROWS];       // fp32 running state (own rows)
    __shared__ u32 cnt_mm[2];              // compute-done counters

    // ---- static A fragments: wave w -> K-slice [128w,128w+128), all 64 rows ----
    const int rbase = b * BROWS;
    bf16x8 afr[4][4];                      // [row-tile][K-tile]
    #pragma unroll
    for (int rt = 0; rt < 4; ++rt) {
        const size_t row = (size_t)(rbase + rt * 16 + colr);
        #pragma unroll
        for (int tt = 0; tt < 4; ++tt) {
            const int kb = wv * 128 + tt * 32 + h8;
            short8 s;
            #pragma unroll
            for (int j = 0; j < 8; ++j) s[j] = (short)f2bf(W[row * UNITS + kb + j]);
            afr[rt][tt] = *(bf16x8*)&s;
        }
    }
    // ---- input A fragment: wave w covers (row-tile w&3, input-K-tile w>>2) ----
    const int rt_in = wv & 3, kt_in = wv >> 2;
    bf16x8 ainf;
    {
        const size_t row = (size_t)(rbase + rt_in * 16 + colr);
        const int kb = kt_in * 32 + h8;
        short8 s;
        #pragma unroll
        for (int j = 0; j < 8; ++j) s[j] = (short)f2bf(Win[row * IN_DIM + kb + j]);
        ainf = *(bf16x8*)&s;
    }

    // ---- pre-loop: deposit bf16(s_0) into own slice, init state/counters ----
    {
        float2 v = *(const float2*)(s0 + tid * 2);
        sB[tid * 2]     = f2bf(v.x);
        sB[tid * 2 + 1] = f2bf(v.y);
    }
    if (tid < BROWS) s_state[tid] = s0[rbase + tid];
    if (tid == 0) { cnt_mm[0] = 0u; cnt_mm[1] = 0u; }
    __syncthreads();   // one-time only

    for (int t = 0; t < T_STEPS; ++t) {
        const int par   = t & 1;
        const u32 epoch = (u32)(t >> 1) + 1u;
        const u32 tag   = (u32)t;

        // ---- issue own poll first (8B = this lane's 2 units) ----
        const u32* pp = buf + par * UNITS + tid * 2;
        u32x2v A;
        if (t > 0)
            asm volatile("global_load_dwordx2 %0, %1, off sc0 sc1"
                         : "=v"(A) : "v"(pp) : "memory");

        // ---- input load overlaps the first poll RTT ----
        const float* ip = inp + (size_t)t * IN_DIM + kt_in * 32 + h8;
        float4 iA = *(const float4*)ip;
        float4 iB = *(const float4*)(ip + 4);

        // ---- spin: detect own 2 tags, redeposit into wave-private LDS slice ----
        if (t > 0) {
            while (true) {
                asm volatile("s_waitcnt vmcnt(0)" : "+v"(A) :: "memory");
                bool ok = ((A[0] >> 16) == tag) & ((A[1] >> 16) == tag);
                if (ok) break;
                asm volatile("global_load_dwordx2 %0, %1, off sc0 sc1"
                             : "=v"(A) : "v"(pp) : "memory");
            }
            u32 pk = (A[0] & 0xFFFFu) | (A[1] << 16);
            *(u32*)&sB[tid * 2] = pk;   // same-wave write -> same-wave read: no barrier
        }

        // ---- MFMAs: 4 row-tile chains; input MFMA seeds chain rt_in ----
        f32x4 acc[4];
        {
            short8 si;
            si[0] = (short)f2bf(iA.x); si[1] = (short)f2bf(iA.y);
            si[2] = (short)f2bf(iA.z); si[3] = (short)f2bf(iA.w);
            si[4] = (short)f2bf(iB.x); si[5] = (short)f2bf(iB.y);
            si[6] = (short)f2bf(iB.z); si[7] = (short)f2bf(iB.w);
            bf16x8 bin = *(bf16x8*)&si;
            f32x4 z = {0.f, 0.f, 0.f, 0.f};
            acc[0] = z; acc[1] = z; acc[2] = z; acc[3] = z;
            acc[rt_in] = __builtin_amdgcn_mfma_f32_16x16x32_bf16(ainf, bin, acc[rt_in], 0, 0, 0);
        }
        #pragma unroll
        for (int tt = 0; tt < 4; ++tt) {
            bf16x8 bb = *(const bf16x8*)&sB[wv * 128 + tt * 32 + h8];
            #pragma unroll
            for (int rt = 0; rt < 4; ++rt)
                acc[rt] = __builtin_amdgcn_mfma_f32_16x16x32_bf16(afr[rt][tt], bb, acc[rt], 0, 0, 0);
        }

        // ---- C partials: col-0 lanes carry all rows (B replicated across cols) ----
        if (colr == 0) {
            #pragma unroll
            for (int rt = 0; rt < 4; ++rt)
                *(f32x4*)&red[par][wv][rt][(lane >> 4) * 4] = acc[rt];
        }
        u32 rtn = 0;
        if (lane == 0)
            rtn = __hip_atomic_fetch_add(&cnt_mm[par], 1u, __ATOMIC_ACQ_REL,
                                         __HIP_MEMORY_SCOPE_WORKGROUP);
        rtn = __shfl(rtn, 0);

        // ---- last-finishing wave finalizes + publishes immediately ----
        if (rtn == (u32)NWAVE * epoch - 1u) {
            const int rt = lane >> 4, rr = lane & 15;
            float pre = 0.f;
            #pragma unroll
            for (int w = 0; w < NWAVE; ++w) pre += red[par][w][rt][rr];
            float e  = __expf(2.0f * pre);
            float th = 1.0f - 2.0f / (e + 1.0f);
            float sn = 0.9f * s_state[lane] + 0.1f * th;
            s_state[lane] = sn;
            const int j = rbase + lane;
            if (t < T_STEPS - 1) {
                u32 word = ((u32)(t + 1) << 16) | (u32)f2bf(sn);
                u32* ps = buf + ((t + 1) & 1) * UNITS + j;   // contiguous 256B/block
                asm volatile("global_store_dword %0, %1, off sc0 sc1"
                             :: "v"(ps), "v"(word) : "memory");
            }
            out[(size_t)t * UNITS + j] = sn;
            if (t == T_STEPS - 1) out[(size_t)T_STEPS * UNITS + j] = sn;
        }
    }
}

extern "C" void kernel_launch(void* const* d_in, const int* in_sizes, int n_in,
                              void* d_out, int out_size, void* d_ws, size_t ws_size,
                              hipStream_t stream) {
    const float* inp = (const float*)d_in[0];   // input_sequence [4096,128]
    const float* s0  = (const float*)d_in[1];   // initial_state  [1,2048]
    const float* W   = (const float*)d_in[2];   // W   [2048,2048]
    const float* Win = (const float*)d_in[3];   // Win [2048,128]
    float* out = (float*)d_out;
    u32* buf = (u32*)d_ws;                      // 2*2048*4 = 16 KiB scratch

    esn_init<<<dim3(16), dim3(256), 0, stream>>>(buf);

    void* args[6];
    args[0] = (void*)&inp; args[1] = (void*)&s0;  args[2] = (void*)&W;
    args[3] = (void*)&Win; args[4] = (void*)&out; args[5] = (void*)&buf;
    hipLaunchCooperativeKernel((void*)esn_step, dim3(NBLK), dim3(TPB), args, 0, stream);
}

// Round 14
// 6086.901 us; speedup vs baseline: 1.7300x; 1.7300x over previous
//
#include <hip/hip_runtime.h>

#define UNITS   2048
#define IN_DIM  128
#define T_STEPS 4096
#define NBLK    64
#define TPB     512
#define BROWS   32    // rows per block

typedef unsigned int u32;
typedef u32 u32x4 __attribute__((ext_vector_type(4)));
typedef u32 u32x2v __attribute__((ext_vector_type(2)));
typedef short short8 __attribute__((ext_vector_type(8)));
typedef __bf16 bf16x8 __attribute__((ext_vector_type(8)));
typedef float f32x4 __attribute__((ext_vector_type(4)));

// Zero comm words each call: tag 0 never matches (first polled tag is 1).
__global__ void esn_init(u32* __restrict__ buf) {
    int i = blockIdx.x * blockDim.x + threadIdx.x;
    if (i < 2 * UNITS) buf[i] = 0u;
}

__device__ __forceinline__ unsigned short f2bf(float f) {   // RNE float->bf16 bits
    u32 x = __float_as_uint(f);
    return (unsigned short)((x + 0x7FFFu + ((x >> 16) & 1u)) >> 16);
}

__global__ void __launch_bounds__(TPB, 2) esn_step(
    const float* __restrict__ inp,   // [4096][128]
    const float* __restrict__ s0,    // [2048]
    const float* __restrict__ W,     // [2048][2048] row-major
    const float* __restrict__ Win,   // [2048][128]
    float* __restrict__ out,         // [4096*2048 + 2048]
    u32* __restrict__ buf)           // [2][2048] packed (tag16|bf16) words
{
    const int b    = blockIdx.x;
    const int tid  = threadIdx.x;
    const int lane = tid & 63;
    const int wv   = tid >> 6;       // wave 0..7, all symmetric
    const int h8   = (lane >> 4) * 8;
    const int colr = lane & 15;

    __shared__ unsigned short sB[UNITS];     // bf16 state; [256w,256w+256) PRIVATE to wave w
    __shared__ float red[2][8][2][16];       // per-wave C partials
    __shared__ float s_state[BROWS];         // fp32 running state (own rows)
    __shared__ u32 cnt_mm[2];                // compute-done counters

    // ---- static A fragments: wave w covers K-slice [256w,256w+256), all 32 rows ----
    const int rbase = b * BROWS;
    bf16x8 a0[8], a1[8];
    #pragma unroll
    for (int tt = 0; tt < 8; ++tt) {
        const int kb = wv * 256 + tt * 32 + h8;
        short8 t0, t1;
        #pragma unroll
        for (int j = 0; j < 8; ++j) {
            t0[j] = (short)f2bf(W[(size_t)(rbase + colr) * UNITS + kb + j]);
            t1[j] = (short)f2bf(W[(size_t)(rbase + 16 + colr) * UNITS + kb + j]);
        }
        a0[tt] = *(bf16x8*)&t0;
        a1[tt] = *(bf16x8*)&t1;
    }
    bf16x8 ain0 = {}, ain1 = {};             // input A tiles (waves 0-3 only)
    const bool hasIn = (wv < 4);
    if (hasIn) {
        const int kb = wv * 32 + h8;
        short8 t0, t1;
        #pragma unroll
        for (int j = 0; j < 8; ++j) {
            t0[j] = (short)f2bf(Win[(size_t)(rbase + colr) * IN_DIM + kb + j]);
            t1[j] = (short)f2bf(Win[(size_t)(rbase + 16 + colr) * IN_DIM + kb + j]);
        }
        ain0 = *(bf16x8*)&t0;
        ain1 = *(bf16x8*)&t1;
    }

    // ---- pre-loop: deposit bf16(s_0) into own slice, init state/counters ----
    {
        float4 v = *(const float4*)(s0 + tid * 4);
        u32x2v pk;
        pk[0] = (u32)f2bf(v.x) | ((u32)f2bf(v.y) << 16);
        pk[1] = (u32)f2bf(v.z) | ((u32)f2bf(v.w) << 16);
        *(u32x2v*)&sB[tid * 4] = pk;
    }
    if (tid < BROWS) s_state[tid] = s0[rbase + tid];
    if (tid == 0) { cnt_mm[0] = 0u; cnt_mm[1] = 0u; }
    __syncthreads();   // one-time only

    // ---- prefetched step-0 input (registers) ----
    float4 iA = {}, iB = {};
    if (hasIn) {
        const float* ip = inp + wv * 32 + h8;
        iA = *(const float4*)ip;
        iB = *(const float4*)(ip + 4);
    }
    u32x4 P;   // probe register: holds the in-flight next-parity probe result

    for (int t = 0; t < T_STEPS; ++t) {
        const int par   = t & 1;
        const u32 epoch = (u32)(t >> 1) + 1u;
        const u32 tag   = (u32)t;
        const u32* pp   = buf + par * UNITS + tid * 4;

        // ---- input MFMAs first (independent of state; inputs prefetched) ----
        f32x4 c0a = {0.f,0.f,0.f,0.f}, c0b = {0.f,0.f,0.f,0.f};
        f32x4 c1a = {0.f,0.f,0.f,0.f}, c1b = {0.f,0.f,0.f,0.f};
        if (hasIn) {
            short8 si;
            si[0] = (short)f2bf(iA.x); si[1] = (short)f2bf(iA.y);
            si[2] = (short)f2bf(iA.z); si[3] = (short)f2bf(iA.w);
            si[4] = (short)f2bf(iB.x); si[5] = (short)f2bf(iB.y);
            si[6] = (short)f2bf(iB.z); si[7] = (short)f2bf(iB.w);
            bf16x8 bin = *(bf16x8*)&si;
            c0b = __builtin_amdgcn_mfma_f32_16x16x32_bf16(ain0, bin, c0b, 0, 0, 0);
            c1b = __builtin_amdgcn_mfma_f32_16x16x32_bf16(ain1, bin, c1b, 0, 0, 0);
        }

        // ---- spin: first sample is the prefetched probe (issued last iter) ----
        if (t > 0) {
            while (true) {
                asm volatile("s_waitcnt vmcnt(0)" : "+v"(P) :: "memory");
                bool ok = ((P[0] >> 16) == tag) & ((P[1] >> 16) == tag)
                        & ((P[2] >> 16) == tag) & ((P[3] >> 16) == tag);
                if (ok) break;
                asm volatile("global_load_dwordx4 %0, %1, off sc0 sc1"
                             : "=v"(P) : "v"(pp) : "memory");
            }
            u32x2v pk;
            pk[0] = (P[0] & 0xFFFFu) | (P[1] << 16);
            pk[1] = (P[2] & 0xFFFFu) | (P[3] << 16);
            *(u32x2v*)&sB[tid * 4] = pk;     // same-wave write -> same-wave read
        }

        // ---- prefetch next-parity probe (crosses MFMA/combine in flight) ----
        if (t < T_STEPS - 1) {
            const u32* pn = buf + ((t + 1) & 1) * UNITS + tid * 4;
            asm volatile("global_load_dwordx4 %0, %1, off sc0 sc1"
                         : "=v"(P) : "v"(pn) : "memory");
        }
        // ---- prefetch next-step input (registers; read-only array) ----
        if (hasIn && t < T_STEPS - 1) {
            const float* ip = inp + (size_t)(t + 1) * IN_DIM + wv * 32 + h8;
            iA = *(const float4*)ip;
            iB = *(const float4*)(ip + 4);
        }

        // ---- 32 state MFMAs in two independent chains per row-tile ----
        #pragma unroll
        for (int tt = 0; tt < 8; ++tt) {
            bf16x8 bb = *(const bf16x8*)&sB[wv * 256 + tt * 32 + h8];
            if (tt & 1) {
                c0b = __builtin_amdgcn_mfma_f32_16x16x32_bf16(a0[tt], bb, c0b, 0, 0, 0);
                c1b = __builtin_amdgcn_mfma_f32_16x16x32_bf16(a1[tt], bb, c1b, 0, 0, 0);
            } else {
                c0a = __builtin_amdgcn_mfma_f32_16x16x32_bf16(a0[tt], bb, c0a, 0, 0, 0);
                c1a = __builtin_amdgcn_mfma_f32_16x16x32_bf16(a1[tt], bb, c1a, 0, 0, 0);
            }
        }
        f32x4 acc0 = c0a + c0b, acc1 = c1a + c1b;

        // ---- C partials: col-0 lanes carry all rows (B replicated across cols) ----
        if (colr == 0) {
            *(f32x4*)&red[par][wv][0][(lane >> 4) * 4] = acc0;
            *(f32x4*)&red[par][wv][1][(lane >> 4) * 4] = acc1;
        }
        u32 rtn = 0;
        if (lane == 0)
            rtn = __hip_atomic_fetch_add(&cnt_mm[par], 1u, __ATOMIC_ACQ_REL,
                                         __HIP_MEMORY_SCOPE_WORKGROUP);
        rtn = __shfl(rtn, 0);

        // ---- last-finishing wave finalizes + publishes immediately ----
        if (rtn == 8u * epoch - 1u && lane < BROWS) {
            const int rt = lane >> 4, rr = lane & 15;
            float pre = 0.f;
            #pragma unroll
            for (int w8 = 0; w8 < 8; ++w8) pre += red[par][w8][rt][rr];
            float e  = __expf(2.0f * pre);
            float th = 1.0f - 2.0f / (e + 1.0f);
            float sn = 0.9f * s_state[lane] + 0.1f * th;
            s_state[lane] = sn;
            const int j = rbase + lane;
            if (t < T_STEPS - 1) {
                u32 word = ((u32)(t + 1) << 16) | (u32)f2bf(sn);
                u32* ps = buf + ((t + 1) & 1) * UNITS + j;   // contiguous 128B/block
                asm volatile("global_store_dword %0, %1, off sc0 sc1"
                             :: "v"(ps), "v"(word) : "memory");
            }
            out[(size_t)t * UNITS + j] = sn;
            if (t == T_STEPS - 1) out[(size_t)T_STEPS * UNITS + j] = sn;
        }
    }
}

extern "C" void kernel_launch(void* const* d_in, const int* in_sizes, int n_in,
                              void* d_out, int out_size, void* d_ws, size_t ws_size,
                              hipStream_t stream) {
    const float* inp = (const float*)d_in[0];   // input_sequence [4096,128]
    const float* s0  = (const float*)d_in[1];   // initial_state  [1,2048]
    const float* W   = (const float*)d_in[2];   // W   [2048,2048]
    const float* Win = (const float*)d_in[3];   // Win [2048,128]
    float* out = (float*)d_out;
    u32* buf = (u32*)d_ws;                      // 2*2048*4 = 16 KiB scratch

    esn_init<<<dim3(16), dim3(256), 0, stream>>>(buf);

    void* args[6];
    args[0] = (void*)&inp; args[1] = (void*)&s0;  args[2] = (void*)&W;
    args[3] = (void*)&Win; args[4] = (void*)&out; args[5] = (void*)&buf;
    hipLaunchCooperativeKernel((void*)esn_step, dim3(NBLK), dim3(TPB), args, 0, stream);
}